// Round 10
// baseline (381.042 us; speedup 1.0000x reference)
//
#include <hip/hip_runtime.h>
#include <stdint.h>

#define L_LAYERS 4
#define BATCH 8
#define PHH 24
#define PWW 24
#define PP (PHH*PWW)        // 576
#define DD 1024
#define ROWS (BATCH*PP)     // 4608
#define OH 336
#define OW 336
#define NTILES 72           // 4608/64  (64-col max groups)
#define TT 36               // 4608/128 (128x128 tiles per dim)
#define NPAIRS (TT*(TT+1)/2)  // 666 upper-triangle tiles
#define NCOMBO 12           // 3 radii x 4 layers
#define TOTBLK (NPAIRS*NCOMBO)   // 7992 = 8 * 999
#define PRESCALE 1024.0f    // fp8 quant prescale (power of 2, exact)
#define INV_PRESCALE2_X2 (1.f/524288.f)   // 2 / PRESCALE^2
#define LSTRIDE 144         // LDS row stride bytes: 9x16B slots (8 data + 1 dead)
                            // -> ds_read positions (r15+2q+h)%8 uniform = conflict-free

typedef __attribute__((ext_vector_type(8))) int i32x8;
typedef __attribute__((ext_vector_type(4))) int i32x4;
typedef __attribute__((ext_vector_type(4))) float f32x4;

// float -> bf16 round-to-nearest-even (raw bits)
__device__ __forceinline__ unsigned int f2bf(float f) {
  unsigned int u = __float_as_uint(f);
  return (u + 0x7FFFu + ((u >> 16) & 1u)) >> 16;
}

// expand 4 bf16 (8 bytes) to 4 floats
__device__ __forceinline__ void load4bf(float* d, const unsigned short* p) {
  const uint2 u = *(const uint2*)p;
  d[0] = __uint_as_float(u.x << 16);
  d[1] = __uint_as_float(u.x & 0xFFFF0000u);
  d[2] = __uint_as_float(u.y << 16);
  d[3] = __uint_as_float(u.y & 0xFFFF0000u);
}

// async global->LDS, 16B per lane. LDS dest is wave-uniform base + lane*16
// (base = first ACTIVE lane) -> never predicate individual lanes off, or the
// whole wave's writes shift by a slot (R9 failure).
__device__ __forceinline__ void async16(const void* g, void* l) {
  __builtin_amdgcn_global_load_lds(
      (const __attribute__((address_space(1))) void*)(size_t)(uintptr_t)g,
      (__attribute__((address_space(3))) void*)(uint32_t)(uintptr_t)l,
      16, 0, 0);
}

// load a 32B fragment from 16B-aligned LDS: two b128 reads + register concat
__device__ __forceinline__ i32x8 ldfrag(const unsigned char* p) {
  const i32x4 lo = *(const i32x4*)p;
  const i32x4 hi = *(const i32x4*)(p + 16);
  return __builtin_shufflevector(lo, hi, 0, 1, 2, 3, 4, 5, 6, 7);
}

// ---------------------------------------------------------------------------
// Kernel 1a: sliding-window vertical pool (reads feat exactly once).
// grid = (16 d-chunks, BATCH, L_LAYERS*2 y-halves); 256 threads.
// Ring of 5 rows x 24 px x 64 dims (f32) in LDS; emits c3 (3-row vertical
// sum) and c5 (5-row vertical sum) as bf16, zero-padded in y.
// ---------------------------------------------------------------------------
__global__ __launch_bounds__(256) void vpool_ring_kernel(
    const float* __restrict__ feat,      // [L][B][PP][DD]
    unsigned short* __restrict__ c3,     // [L][ROWS][DD] bf16 bits
    unsigned short* __restrict__ c5) {   // [L][ROWS][DD] bf16 bits
  const int dch = blockIdx.x;            // 64-dim chunk
  const int b = blockIdx.y;
  const int l = blockIdx.z >> 1;
  const int half = blockIdx.z & 1;
  const int py0 = half * 12, py1 = py0 + 11;
  const int t = threadIdx.x;
  const int pxg = t >> 5;                // 0..7
  const int d2 = t & 31;                 // float2 index within 64-dim chunk

  __shared__ float ring[5][24 * 64];

  const float* fb = feat + ((size_t)l * BATCH + b) * PP * DD + dch * 64 + d2 * 2;

  // preload rows py0-2 .. py0+1 (skip OOB)
  for (int yy = py0 - 2; yy <= py0 + 1; ++yy) {
    if (yy < 0) continue;
    #pragma unroll
    for (int i = 0; i < 3; ++i) {
      int px = i * 8 + pxg;
      *(float2*)&ring[yy % 5][px * 64 + d2 * 2] =
          *(const float2*)(fb + (size_t)(yy * PWW + px) * DD);
    }
  }
  for (int py = py0; py <= py1; ++py) {
    const int yl = py + 2;
    if (yl < PHH) {
      __syncthreads();   // slot (py+2)%5 == (py-3)%5 was read last iteration
      #pragma unroll
      for (int i = 0; i < 3; ++i) {
        int px = i * 8 + pxg;
        *(float2*)&ring[yl % 5][px * 64 + d2 * 2] =
            *(const float2*)(fb + (size_t)(yl * PWW + px) * DD);
      }
    }
    __syncthreads();
    #pragma unroll
    for (int i = 0; i < 3; ++i) {
      int px = i * 8 + pxg;
      float s3x = 0.f, s3y = 0.f, s5x = 0.f, s5y = 0.f;
      #pragma unroll
      for (int dy = -2; dy <= 2; ++dy) {
        int yy = py + dy;
        if (yy < 0 || yy >= PHH) continue;
        float2 v = *(const float2*)&ring[yy % 5][px * 64 + d2 * 2];
        s5x += v.x; s5y += v.y;
        if (dy >= -1 && dy <= 1) { s3x += v.x; s3y += v.y; }
      }
      const size_t idx =
          ((size_t)l * ROWS + b * PP + py * PWW + px) * DD + dch * 64 + d2 * 2;
      *(unsigned int*)&c3[idx] = f2bf(s3x) | (f2bf(s3y) << 16);
      *(unsigned int*)&c5[idx] = f2bf(s5x) | (f2bf(s5y) << 16);
    }
  }
}

// ---------------------------------------------------------------------------
// Kernel 1b: sliding-window horizontal pool + L2-normalize + fp8(e4m3)
// quantize (x PRESCALE). One block per (l, b, py); marches px 0..23 keeping
// 3-col (c3) and 5-col (c5) register windows -> feat/c3/c5 read exactly once.
// 256 thr x 4 dims; per-px block-wide norm reduction (4 waves).
// ---------------------------------------------------------------------------
__global__ __launch_bounds__(256) void hpool_slide_kernel(
    const float* __restrict__ feat,
    const unsigned short* __restrict__ c3,
    const unsigned short* __restrict__ c5,
    unsigned char* __restrict__ nf_all) {    // [NCOMBO][ROWS][DD] fp8
  const int rb = blockIdx.x;               // b*PHH + py
  const int l = blockIdx.y;
  const int b = rb / PHH, py = rb % PHH;
  const int t = threadIdx.x;
  const int lane = t & 63, w = t >> 6;
  const int d0 = t * 4;
  const size_t rowbase = (size_t)b * PP + (size_t)py * PWW;  // global row at px=0

  const float* fb = feat + ((size_t)l * BATCH * PP + rowbase) * DD + d0;
  const unsigned short* c3b = c3 + ((size_t)l * ROWS + rowbase) * DD + d0;
  const unsigned short* c5b = c5 + ((size_t)l * ROWS + rowbase) * DD + d0;
  unsigned char* nf1 = nf_all + (((size_t)(0*L_LAYERS + l) * ROWS + rowbase) * DD + d0);
  unsigned char* nf3 = nf_all + (((size_t)(1*L_LAYERS + l) * ROWS + rowbase) * DD + d0);
  unsigned char* nf5 = nf_all + (((size_t)(2*L_LAYERS + l) * ROWS + rowbase) * DD + d0);

  float w3[3][4] = {{0,0,0,0},{0,0,0,0},{0,0,0,0}};
  float w5[5][4] = {{0,0,0,0},{0,0,0,0},{0,0,0,0},{0,0,0,0},{0,0,0,0}};
  load4bf(w3[1], c3b);                 // col 0
  load4bf(w3[2], c3b + DD);            // col 1
  load4bf(w5[2], c5b);                 // col 0
  load4bf(w5[3], c5b + DD);            // col 1
  load4bf(w5[4], c5b + 2 * DD);        // col 2

  __shared__ float red[4][3];

  for (int px = 0; px < PWW; ++px) {
    float s1[4], s3[4], s5[4];
    const float4 f = *(const float4*)(fb + (size_t)px * DD);
    s1[0] = f.x; s1[1] = f.y; s1[2] = f.z; s1[3] = f.w;
    #pragma unroll
    for (int j = 0; j < 4; ++j) {
      s3[j] = w3[0][j] + w3[1][j] + w3[2][j];
      s5[j] = w5[0][j] + w5[1][j] + w5[2][j] + w5[3][j] + w5[4][j];
    }
    float q1 = 0, q3 = 0, q5 = 0;
    #pragma unroll
    for (int j = 0; j < 4; ++j) {
      q1 += s1[j]*s1[j]; q3 += s3[j]*s3[j]; q5 += s5[j]*s5[j];
    }
    #pragma unroll
    for (int off = 32; off > 0; off >>= 1) {
      q1 += __shfl_down(q1, off);
      q3 += __shfl_down(q3, off);
      q5 += __shfl_down(q5, off);
    }
    __syncthreads();   // protect red[] from previous iteration's readers
    if (lane == 0) { red[w][0] = q1; red[w][1] = q3; red[w][2] = q5; }
    __syncthreads();
    const float rn1 = rsqrtf(red[0][0] + red[1][0] + red[2][0] + red[3][0]) * PRESCALE;
    const float rn3 = rsqrtf(red[0][1] + red[1][1] + red[2][1] + red[3][1]) * PRESCALE;
    const float rn5 = rsqrtf(red[0][2] + red[1][2] + red[2][2] + red[3][2]) * PRESCALE;

    const size_t po = (size_t)px * DD;
    unsigned int o;
    o = __builtin_amdgcn_cvt_pk_fp8_f32(s1[0]*rn1, s1[1]*rn1, 0, false);
    o = __builtin_amdgcn_cvt_pk_fp8_f32(s1[2]*rn1, s1[3]*rn1, o, true);
    *(unsigned int*)(nf1 + po) = o;
    o = __builtin_amdgcn_cvt_pk_fp8_f32(s3[0]*rn3, s3[1]*rn3, 0, false);
    o = __builtin_amdgcn_cvt_pk_fp8_f32(s3[2]*rn3, s3[3]*rn3, o, true);
    *(unsigned int*)(nf3 + po) = o;
    o = __builtin_amdgcn_cvt_pk_fp8_f32(s5[0]*rn5, s5[1]*rn5, 0, false);
    o = __builtin_amdgcn_cvt_pk_fp8_f32(s5[2]*rn5, s5[3]*rn5, o, true);
    *(unsigned int*)(nf5 + po) = o;

    // slide windows
    #pragma unroll
    for (int j = 0; j < 4; ++j) { w3[0][j] = w3[1][j]; w3[1][j] = w3[2][j]; }
    if (px + 2 < PWW) load4bf(w3[2], c3b + (size_t)(px + 2) * DD);
    else { w3[2][0]=0; w3[2][1]=0; w3[2][2]=0; w3[2][3]=0; }
    #pragma unroll
    for (int i = 0; i < 4; ++i)
      #pragma unroll
      for (int j = 0; j < 4; ++j) w5[i][j] = w5[i+1][j];
    if (px + 3 < PWW) load4bf(w5[4], c5b + (size_t)(px + 3) * DD);
    else { w5[4][0]=0; w5[4][1]=0; w5[4][2]=0; w5[4][3]=0; }
  }
}

// ---------------------------------------------------------------------------
// Kernel 2: symmetric Gram GEMM, MX-fp8 (e4m3, unity E8M0 scales), K-tile=128.
// 1D grid, XCD-aware swizzle; upper-triangle 128x128 tiles; same-image pairs
// dead -> exit. LDS rows at 144B stride (8 identity 16B data slots + 1 dead):
// ds_read_b128 phase positions (r15+2q+h)%8 are uniform -> conflict-free.
// Staging: ALL 64 lanes of each wave active (dead slot writes a duplicate of
// chunk 7 -- R9's per-lane predication shifted the wave-uniform LDS base).
// The only predicate (c < 1152) masks whole waves (boundary on a wave edge).
// Fragments: 2x i32x4 deref + shufflevector concat (registers, no scratch).
// 36.9KB LDS -> 4 blocks/CU co-resident.
// Fused row-max per 64-col group + col-max (transposed tile's row-max).
// ---------------------------------------------------------------------------
__global__ __launch_bounds__(256, 4) void gemm_max_kernel(
    const unsigned char* __restrict__ nf_all,   // [NCOMBO][ROWS][DD] fp8
    float* __restrict__ part) {                 // [NCOMBO][ROWS][NTILES]
  // XCD-aware swizzle (speed-only heuristic; every slot computed once)
  const int bid = blockIdx.x;
  const int slot = (bid & 7) * (TOTBLK / 8) + (bid >> 3);
  const int combo = slot / NPAIRS;
  int rem = slot % NPAIRS;
  int it = 0;
  while (rem >= TT - it) { rem -= TT - it; ++it; }
  const int jt = it + rem;
  const int row0 = it * 128;
  const int col0 = jt * 128;

  // dead-tile check: both tiles fully inside the same image -> never read
  {
    const bool inA = (row0 / PP) == ((row0 + 127) / PP);
    const bool inB = (col0 / PP) == ((col0 + 127) / PP);
    if (inA && inB && (row0 / PP) == (col0 / PP)) return;
  }

  __shared__ unsigned char As[128 * LSTRIDE];
  __shared__ unsigned char Bs[128 * LSTRIDE];

  const int t = threadIdx.x;
  const int lane = t & 63;
  const int wave = t >> 6;
  const int wm = wave >> 1;    // row half (64 rows)
  const int wn = wave & 1;     // col half (64 cols)

  const unsigned char* nf = nf_all + (size_t)combo * ROWS * DD;
  float* partialL = part + (size_t)combo * ROWS * NTILES;

  const f32x4 zero = {0.f, 0.f, 0.f, 0.f};
  f32x4 acc[4][4];
  #pragma unroll
  for (int m = 0; m < 4; ++m)
    #pragma unroll
    for (int n = 0; n < 4; ++n) acc[m][n] = zero;

  const unsigned char* gA = nf + (size_t)row0 * DD;
  const unsigned char* gB = nf + (size_t)col0 * DD;

  // lane-constant fragment bases: row = (wm|wn)*64 + r15, byte offset q*32
  const int r15 = lane & 15;
  const int qo = (lane >> 4) * 32;
  const unsigned char* Abase = As + (wm * 64 + r15) * LSTRIDE + qo;
  const unsigned char* Bbase = Bs + (wn * 64 + r15) * LSTRIDE + qo;

  for (int kt = 0; kt < DD / 128; ++kt) {
    const int k0 = kt * 128;
    // 128 rows x 9 slots = 1152 16B-chunks per matrix; chunk c: row=c/9,
    // sl=c%9; slots 0..7 hold K-chunks 0..7 in order; slot 8 (dead) stages a
    // duplicate of chunk 7 so every lane stays active (never read back).
    #pragma unroll
    for (int i = 0; i < 5; ++i) {
      int c = i * 256 + t;
      if (c < 1152) {
        int row = c / 9, sl = c % 9;
        int g = sl - (sl >> 3);    // 8 -> 7, else identity (branchless clamp)
        async16(gA + (size_t)row * DD + k0 + g * 16, &As[c * 16]);
      }
    }
    #pragma unroll
    for (int i = 0; i < 5; ++i) {
      int c = i * 256 + t;
      if (c < 1152) {
        int row = c / 9, sl = c % 9;
        int g = sl - (sl >> 3);
        async16(gB + (size_t)row * DD + k0 + g * 16, &Bs[c * 16]);
      }
    }
    __syncthreads();   // drains vmcnt (global_load_lds) + barrier

    const i32x8 a0 = ldfrag(Abase);
    const i32x8 a1 = ldfrag(Abase + 16 * LSTRIDE);
    const i32x8 a2 = ldfrag(Abase + 32 * LSTRIDE);
    const i32x8 a3 = ldfrag(Abase + 48 * LSTRIDE);
    #pragma unroll
    for (int n = 0; n < 4; ++n) {
      const i32x8 bn = ldfrag(Bbase + n * 16 * LSTRIDE);
      acc[0][n] = __builtin_amdgcn_mfma_scale_f32_16x16x128_f8f6f4(
          a0, bn, acc[0][n], 0, 0, 0, 0x7F7F7F7F, 0, 0x7F7F7F7F);
      acc[1][n] = __builtin_amdgcn_mfma_scale_f32_16x16x128_f8f6f4(
          a1, bn, acc[1][n], 0, 0, 0, 0x7F7F7F7F, 0, 0x7F7F7F7F);
      acc[2][n] = __builtin_amdgcn_mfma_scale_f32_16x16x128_f8f6f4(
          a2, bn, acc[2][n], 0, 0, 0, 0x7F7F7F7F, 0, 0x7F7F7F7F);
      acc[3][n] = __builtin_amdgcn_mfma_scale_f32_16x16x128_f8f6f4(
          a3, bn, acc[3][n], 0, 0, 0, 0x7F7F7F7F, 0, 0x7F7F7F7F);
    }
    __syncthreads();
  }

  // C/D layout: col = lane&15, row = (lane>>4)*4 + reg (shape-determined)
  // Row-max over this wave's 64 cols (group 2*jt+wn).
  #pragma unroll
  for (int m = 0; m < 4; ++m) {
    #pragma unroll
    for (int g = 0; g < 4; ++g) {
      float v = fmaxf(fmaxf(acc[m][0][g], acc[m][1][g]),
                      fmaxf(acc[m][2][g], acc[m][3][g]));
      v = fmaxf(v, __shfl_xor(v, 1));
      v = fmaxf(v, __shfl_xor(v, 2));
      v = fmaxf(v, __shfl_xor(v, 4));
      v = fmaxf(v, __shfl_xor(v, 8));
      if ((lane & 15) == 0) {
        int row = row0 + wm * 64 + m * 16 + (lane >> 4) * 4 + g;
        partialL[(size_t)row * NTILES + 2 * jt + wn] = v;
      }
    }
  }
  // Col-max over this wave's 64 rows (group 2*it+wm), written transposed.
  if (it != jt) {
    #pragma unroll
    for (int n = 0; n < 4; ++n) {
      float v = -1e30f;
      #pragma unroll
      for (int m = 0; m < 4; ++m)
        #pragma unroll
        for (int g = 0; g < 4; ++g) v = fmaxf(v, acc[m][n][g]);
      v = fmaxf(v, __shfl_xor(v, 16));
      v = fmaxf(v, __shfl_xor(v, 32));
      if (lane < 16) {
        int col = col0 + wn * 64 + n * 16 + lane;
        partialL[(size_t)col * NTILES + 2 * it + wm] = v;
      }
    }
  }
}

// ---------------------------------------------------------------------------
// Kernel 3: per row: for each of 12 combos, max over 9 q-groups per image c,
// d-transform (undo fp8 prescale), top-2 smallest over c != b; sum -> scores.
// ---------------------------------------------------------------------------
__global__ __launch_bounds__(256) void reduce_topk_kernel(
    const float* __restrict__ part,      // [NCOMBO][ROWS][NTILES]
    float* __restrict__ scores) {        // [ROWS]
  const int row = blockIdx.x * 256 + threadIdx.x;
  if (row >= ROWS) return;
  const int b = row / PP;
  float sum = 0.f;
  for (int k = 0; k < NCOMBO; ++k) {
    const float* pr = part + ((size_t)k * ROWS + row) * NTILES;
    float d1 = 1e30f, d2 = 1e30f;
    #pragma unroll
    for (int c = 0; c < BATCH; ++c) {
      if (c == b) continue;
      float md = pr[c * 9];
      #pragma unroll
      for (int q = 1; q < 9; ++q) md = fmaxf(md, pr[c * 9 + q]);
      float d = sqrtf(fmaxf(2.f - md * INV_PRESCALE2_X2, 0.f));
      if (d < d1) { d2 = d1; d1 = d; }
      else if (d < d2) { d2 = d; }
    }
    sum += 0.5f * (d1 + d2);
  }
  scores[row] = sum;
}

// ---------------------------------------------------------------------------
// Kernel 4: scores_image[b] = max_p scores[b,p] / 12
// ---------------------------------------------------------------------------
__global__ __launch_bounds__(256) void image_max_kernel(
    const float* __restrict__ scores, float* __restrict__ out) {
  const int b = blockIdx.x;
  const int t = threadIdx.x;
  float m = -1e30f;
  for (int p = t; p < PP; p += 256) m = fmaxf(m, scores[b * PP + p]);
  #pragma unroll
  for (int off = 32; off > 0; off >>= 1) m = fmaxf(m, __shfl_down(m, off));
  __shared__ float red[4];
  if ((t & 63) == 0) red[t >> 6] = m;
  __syncthreads();
  if (t == 0)
    out[b] = fmaxf(fmaxf(red[0], red[1]), fmaxf(red[2], red[3])) * (1.f / 12.f);
}

// ---------------------------------------------------------------------------
// Kernel 5: bilinear (align_corners) 24x24 -> 336x336, scale 1/12
// ---------------------------------------------------------------------------
__global__ __launch_bounds__(256) void upsample_kernel(
    const float* __restrict__ scores, float* __restrict__ out) {
  const int idx = blockIdx.x * 256 + threadIdx.x;
  if (idx >= BATCH * OH * OW) return;
  const int b = idx / (OH * OW);
  const int rem = idx % (OH * OW);
  const int y = rem / OW, x = rem % OW;
  const float sc = (float)(23.0 / 335.0);
  const float ys = y * sc, xs = x * sc;
  const int y0 = (int)floorf(ys), x0 = (int)floorf(xs);
  const float wy = ys - (float)y0, wx = xs - (float)x0;
  const int y1 = min(y0 + 1, PHH - 1), x1 = min(x0 + 1, PWW - 1);
  const float* sb = scores + b * PP;
  const float f00 = sb[y0 * PWW + x0], f01 = sb[y0 * PWW + x1];
  const float f10 = sb[y1 * PWW + x0], f11 = sb[y1 * PWW + x1];
  const float v = f00 * (1.f - wy) * (1.f - wx) + f01 * (1.f - wy) * wx +
                  f10 * wy * (1.f - wx) + f11 * wy * wx;
  out[8 + idx] = v * (1.f / 12.f);
}

// ---------------------------------------------------------------------------
extern "C" void kernel_launch(void* const* d_in, const int* in_sizes, int n_in,
                              void* d_out, int out_size, void* d_ws, size_t ws_size,
                              hipStream_t stream) {
  const float* feat = (const float*)d_in[0];     // [4][8][576][1024] f32
  float* out = (float*)d_out;                    // [8] ++ [8][336][336]
  char* ws = (char*)d_ws;

  // workspace layout (~148 MB of ~302 MB)
  const size_t NF_BYTES   = (size_t)NCOMBO * ROWS * DD;            // 56,623,104 (fp8)
  const size_t PART_BYTES = (size_t)NCOMBO * ROWS * NTILES * 4;    // 15,925,248
  const size_t SCR_BYTES  = (size_t)ROWS * 4;                      //     18,432
  const size_t C_BYTES    = (size_t)L_LAYERS * ROWS * DD * 2;      // 37,748,736
  unsigned char*  nf_all = (unsigned char*)ws;
  float*          part   = (float*)(ws + NF_BYTES);
  float*          scr    = (float*)(ws + NF_BYTES + PART_BYTES);
  unsigned short* c3     = (unsigned short*)(ws + NF_BYTES + PART_BYTES + SCR_BYTES);
  unsigned short* c5     = (unsigned short*)(ws + NF_BYTES + PART_BYTES + SCR_BYTES + C_BYTES);

  vpool_ring_kernel<<<dim3(16, BATCH, L_LAYERS * 2), 256, 0, stream>>>(feat, c3, c5);
  hpool_slide_kernel<<<dim3(PHH * BATCH, L_LAYERS), 256, 0, stream>>>(feat, c3, c5, nf_all);
  gemm_max_kernel<<<TOTBLK, 256, 0, stream>>>(nf_all, part);
  reduce_topk_kernel<<<(ROWS + 255) / 256, 256, 0, stream>>>(part, scr);
  image_max_kernel<<<BATCH, 256, 0, stream>>>(scr, out);
  upsample_kernel<<<(BATCH * OH * OW + 255) / 256, 256, 0, stream>>>(scr, out);
}

// Round 11
// 360.881 us; speedup vs baseline: 1.0559x; 1.0559x over previous
//
#include <hip/hip_runtime.h>
#include <stdint.h>

#define L_LAYERS 4
#define BATCH 8
#define PHH 24
#define PWW 24
#define PP (PHH*PWW)        // 576
#define DD 1024
#define ROWS (BATCH*PP)     // 4608
#define OH 336
#define OW 336
#define NTILES 72           // 4608/64  (64-col max groups)
#define TT 36               // 4608/128 (128x128 tiles per dim)
#define NPAIRS (TT*(TT+1)/2)  // 666 upper-triangle tiles
#define NCOMBO 12           // 3 radii x 4 layers
#define TOTBLK (NPAIRS*NCOMBO)   // 7992 = 8 * 999
#define PRESCALE 1024.0f    // fp8 quant prescale (power of 2, exact)
#define INV_PRESCALE2_X2 (1.f/524288.f)   // 2 / PRESCALE^2

typedef __attribute__((ext_vector_type(8))) int i32x8;
typedef __attribute__((ext_vector_type(4))) float f32x4;

// float -> bf16 round-to-nearest-even (raw bits)
__device__ __forceinline__ unsigned int f2bf(float f) {
  unsigned int u = __float_as_uint(f);
  return (u + 0x7FFFu + ((u >> 16) & 1u)) >> 16;
}

__device__ __forceinline__ float bflo(unsigned int w) {
  return __uint_as_float(w << 16);
}
__device__ __forceinline__ float bfhi(unsigned int w) {
  return __uint_as_float(w & 0xFFFF0000u);
}

// expand 4 bf16 (8 bytes) to 4 floats
__device__ __forceinline__ void load4bf(float* d, const unsigned short* p) {
  const uint2 u = *(const uint2*)p;
  d[0] = bflo(u.x); d[1] = bfhi(u.x);
  d[2] = bflo(u.y); d[3] = bfhi(u.y);
}

// async global->LDS, 16B per lane. LDS dest is wave-uniform base + lane*16
// (base = first ACTIVE lane) -> never predicate individual lanes off (R9).
__device__ __forceinline__ void async16(const void* g, void* l) {
  __builtin_amdgcn_global_load_lds(
      (const __attribute__((address_space(1))) void*)(size_t)(uintptr_t)g,
      (__attribute__((address_space(3))) void*)(uint32_t)(uintptr_t)l,
      16, 0, 0);
}

// ---------------------------------------------------------------------------
// Kernel 1: sliding-window pool, BOTH axes (reads feat exactly once).
// grid = (16 d-chunks, BATCH, L_LAYERS*2 y-halves); 256 threads.
// Ring of 5 rows x 24 px x 64 dims (f32) in LDS -> vertical sums v3/v5,
// packed bf16 into a 24-px LDS row -> horizontal 3/5 windows -> h3/h5 out.
// (Numerics identical to prior c3/c5 path: vertical sum rounded to bf16,
// horizontal sum in fp32.)
// ---------------------------------------------------------------------------
__global__ __launch_bounds__(256) void pool_kernel(
    const float* __restrict__ feat,      // [L][B][PP][DD]
    unsigned short* __restrict__ h3,     // [L][ROWS][DD] bf16 bits (3x3 sum)
    unsigned short* __restrict__ h5) {   // [L][ROWS][DD] bf16 bits (5x5 sum)
  const int dch = blockIdx.x;            // 64-dim chunk
  const int b = blockIdx.y;
  const int l = blockIdx.z >> 1;
  const int half = blockIdx.z & 1;
  const int py0 = half * 12, py1 = py0 + 11;
  const int t = threadIdx.x;
  const int pxg = t >> 5;                // 0..7
  const int d2 = t & 31;                 // float2 index within 64-dim chunk

  __shared__ float ring[5][24 * 64];     // 30 KB
  __shared__ unsigned int v3p[24 * 32];  // 3 KB packed bf16 pairs
  __shared__ unsigned int v5p[24 * 32];  // 3 KB

  const float* fb = feat + ((size_t)l * BATCH + b) * PP * DD + dch * 64 + d2 * 2;

  // preload rows py0-2 .. py0+1 (skip OOB)
  for (int yy = py0 - 2; yy <= py0 + 1; ++yy) {
    if (yy < 0) continue;
    #pragma unroll
    for (int i = 0; i < 3; ++i) {
      int px = i * 8 + pxg;
      *(float2*)&ring[yy % 5][px * 64 + d2 * 2] =
          *(const float2*)(fb + (size_t)(yy * PWW + px) * DD);
    }
  }
  for (int py = py0; py <= py1; ++py) {
    const int yl = py + 2;
    if (yl < PHH) {
      __syncthreads();   // slot being overwritten was read last iteration
      #pragma unroll
      for (int i = 0; i < 3; ++i) {
        int px = i * 8 + pxg;
        *(float2*)&ring[yl % 5][px * 64 + d2 * 2] =
            *(const float2*)(fb + (size_t)(yl * PWW + px) * DD);
      }
    }
    __syncthreads();     // ring writes visible; also protects v3p/v5p reuse
    // vertical phase: v3/v5 sums -> packed bf16 LDS row
    #pragma unroll
    for (int i = 0; i < 3; ++i) {
      int px = i * 8 + pxg;
      float s3x = 0.f, s3y = 0.f, s5x = 0.f, s5y = 0.f;
      #pragma unroll
      for (int dy = -2; dy <= 2; ++dy) {
        int yy = py + dy;
        if (yy < 0 || yy >= PHH) continue;
        float2 v = *(const float2*)&ring[yy % 5][px * 64 + d2 * 2];
        s5x += v.x; s5y += v.y;
        if (dy >= -1 && dy <= 1) { s3x += v.x; s3y += v.y; }
      }
      v3p[px * 32 + d2] = f2bf(s3x) | (f2bf(s3y) << 16);
      v5p[px * 32 + d2] = f2bf(s5x) | (f2bf(s5y) << 16);
    }
    __syncthreads();     // v-rows visible
    // horizontal phase: 3/5-col windows over packed rows -> global h3/h5
    #pragma unroll
    for (int i = 0; i < 3; ++i) {
      int px = i * 8 + pxg;
      float h3x = 0.f, h3y = 0.f, h5x = 0.f, h5y = 0.f;
      #pragma unroll
      for (int dx = -2; dx <= 2; ++dx) {
        int xx = px + dx;
        if (xx < 0 || xx >= PWW) continue;
        unsigned int w5 = v5p[xx * 32 + d2];
        h5x += bflo(w5); h5y += bfhi(w5);
        if (dx >= -1 && dx <= 1) {
          unsigned int w3 = v3p[xx * 32 + d2];
          h3x += bflo(w3); h3y += bfhi(w3);
        }
      }
      const size_t idx =
          ((size_t)l * ROWS + b * PP + py * PWW + px) * DD + dch * 64 + d2 * 2;
      *(unsigned int*)&h3[idx] = f2bf(h3x) | (f2bf(h3y) << 16);
      *(unsigned int*)&h5[idx] = f2bf(h5x) | (f2bf(h5y) << 16);
    }
  }
}

// ---------------------------------------------------------------------------
// Kernel 2: normalize + fp8(e4m3) quantize (x PRESCALE), one block per
// (l, row) = 18432 blocks (24x the parallelism of the old serial-px hpool).
// Pure streaming: read feat row + h3 + h5, block-reduce 3 squared norms,
// write 3 fp8 rows. 2 barriers total.
// ---------------------------------------------------------------------------
__global__ __launch_bounds__(256) void quant_kernel(
    const float* __restrict__ feat,
    const unsigned short* __restrict__ h3,
    const unsigned short* __restrict__ h5,
    unsigned char* __restrict__ nf_all) {    // [NCOMBO][ROWS][DD] fp8
  const int row = blockIdx.x;
  const int l = blockIdx.y;
  const int t = threadIdx.x;
  const int lane = t & 63, w = t >> 6;
  const int d0 = t * 4;
  const size_t lro = ((size_t)l * ROWS + row) * DD + d0;

  float s1[4], s3[4], s5[4];
  {
    const float4 f = *(const float4*)(feat + lro);  // l*ROWS+row == (l*B+b)*PP+p
    s1[0] = f.x; s1[1] = f.y; s1[2] = f.z; s1[3] = f.w;
  }
  load4bf(s3, h3 + lro);
  load4bf(s5, h5 + lro);

  float q1 = 0.f, q3 = 0.f, q5 = 0.f;
  #pragma unroll
  for (int j = 0; j < 4; ++j) {
    q1 += s1[j]*s1[j]; q3 += s3[j]*s3[j]; q5 += s5[j]*s5[j];
  }
  #pragma unroll
  for (int off = 32; off > 0; off >>= 1) {
    q1 += __shfl_down(q1, off);
    q3 += __shfl_down(q3, off);
    q5 += __shfl_down(q5, off);
  }
  __shared__ float red[4][3];
  if (lane == 0) { red[w][0] = q1; red[w][1] = q3; red[w][2] = q5; }
  __syncthreads();
  const float rn1 = rsqrtf(red[0][0] + red[1][0] + red[2][0] + red[3][0]) * PRESCALE;
  const float rn3 = rsqrtf(red[0][1] + red[1][1] + red[2][1] + red[3][1]) * PRESCALE;
  const float rn5 = rsqrtf(red[0][2] + red[1][2] + red[2][2] + red[3][2]) * PRESCALE;

  const size_t ro = (size_t)row * DD + d0;
  unsigned int o;
  o = __builtin_amdgcn_cvt_pk_fp8_f32(s1[0]*rn1, s1[1]*rn1, 0, false);
  o = __builtin_amdgcn_cvt_pk_fp8_f32(s1[2]*rn1, s1[3]*rn1, o, true);
  *(unsigned int*)(nf_all + (size_t)(0*L_LAYERS + l) * ROWS * DD + ro) = o;
  o = __builtin_amdgcn_cvt_pk_fp8_f32(s3[0]*rn3, s3[1]*rn3, 0, false);
  o = __builtin_amdgcn_cvt_pk_fp8_f32(s3[2]*rn3, s3[3]*rn3, o, true);
  *(unsigned int*)(nf_all + (size_t)(1*L_LAYERS + l) * ROWS * DD + ro) = o;
  o = __builtin_amdgcn_cvt_pk_fp8_f32(s5[0]*rn5, s5[1]*rn5, 0, false);
  o = __builtin_amdgcn_cvt_pk_fp8_f32(s5[2]*rn5, s5[3]*rn5, o, true);
  *(unsigned int*)(nf_all + (size_t)(2*L_LAYERS + l) * ROWS * DD + ro) = o;
}

// ---------------------------------------------------------------------------
// Kernel 3: symmetric Gram GEMM, MX-fp8 (e4m3, unity E8M0 scales), K-tile=128.
// R8-exact (measured 164 us): 1D grid + XCD swizzle; upper-triangle 128x128
// tiles; same-image pairs dead -> exit. 32B-granule XOR swizzle (j^(row&6))
// -> each lane's 32 K-bytes contiguous+32B-aligned -> single i32x8 deref.
// NOTE: SQ_LDS_BANK_CONFLICT ~1.44e7 here is the staging-WRITE burst
// serialization of global_load_lds (8 lanes/bank per 1KB wave write) --
// layout-independent (proved by R10's 144B-stride probe), not a ds_read
// problem. Not a target.
// Fused row-max per 64-col group + col-max (transposed tile's row-max).
// ---------------------------------------------------------------------------
__global__ __launch_bounds__(256, 3) void gemm_max_kernel(
    const unsigned char* __restrict__ nf_all,   // [NCOMBO][ROWS][DD] fp8
    float* __restrict__ part) {                 // [NCOMBO][ROWS][NTILES]
  // XCD-aware swizzle (speed-only heuristic; every slot computed once)
  const int bid = blockIdx.x;
  const int slot = (bid & 7) * (TOTBLK / 8) + (bid >> 3);
  const int combo = slot / NPAIRS;
  int rem = slot % NPAIRS;
  int it = 0;
  while (rem >= TT - it) { rem -= TT - it; ++it; }
  const int jt = it + rem;
  const int row0 = it * 128;
  const int col0 = jt * 128;

  // dead-tile check: both tiles fully inside the same image -> never read
  {
    const bool inA = (row0 / PP) == ((row0 + 127) / PP);
    const bool inB = (col0 / PP) == ((col0 + 127) / PP);
    if (inA && inB && (row0 / PP) == (col0 / PP)) return;
  }

  __shared__ unsigned char As[128 * 128];
  __shared__ unsigned char Bs[128 * 128];

  const int t = threadIdx.x;
  const int lane = t & 63;
  const int wave = t >> 6;
  const int wm = wave >> 1;    // row half (64 rows)
  const int wn = wave & 1;     // col half (64 cols)

  const unsigned char* nf = nf_all + (size_t)combo * ROWS * DD;
  float* partialL = part + (size_t)combo * ROWS * NTILES;

  const f32x4 zero = {0.f, 0.f, 0.f, 0.f};
  f32x4 acc[4][4];
  #pragma unroll
  for (int m = 0; m < 4; ++m)
    #pragma unroll
    for (int n = 0; n < 4; ++n) acc[m][n] = zero;

  const unsigned char* gA = nf + (size_t)row0 * DD;
  const unsigned char* gB = nf + (size_t)col0 * DD;

  // lane-constant LDS fragment offset: 32B granule (2q) ^ (r15 & 6)
  const int r15 = lane & 15;
  const int loff = ((((lane >> 4) << 1) ^ (r15 & 6)) << 4);
  const unsigned char* Abase = As + (size_t)(wm * 64 + r15) * 128 + loff;
  const unsigned char* Bbase = Bs + (size_t)(wn * 64 + r15) * 128 + loff;

  for (int kt = 0; kt < DD / 128; ++kt) {
    const int k0 = kt * 128;
    // 128 rows x 128 B = 1024 16B-chunks per matrix; chunk c: row=c>>3,
    // slot j=c&7 holds global chunk j ^ (row&6)  (32B-granule XOR swizzle)
    #pragma unroll
    for (int i = 0; i < 4; ++i) {
      int c = i * 256 + t;
      int row = c >> 3, j = c & 7;
      int g = j ^ (row & 6);
      async16(gA + (size_t)row * DD + k0 + g * 16, &As[c * 16]);
    }
    #pragma unroll
    for (int i = 0; i < 4; ++i) {
      int c = i * 256 + t;
      int row = c >> 3, j = c & 7;
      int g = j ^ (row & 6);
      async16(gB + (size_t)row * DD + k0 + g * 16, &Bs[c * 16]);
    }
    __syncthreads();   // drains vmcnt (global_load_lds) + barrier

    const i32x8 a0 = *(const i32x8*)(Abase +    0);
    const i32x8 a1 = *(const i32x8*)(Abase + 2048);
    const i32x8 a2 = *(const i32x8*)(Abase + 4096);
    const i32x8 a3 = *(const i32x8*)(Abase + 6144);
    #pragma unroll
    for (int n = 0; n < 4; ++n) {
      const i32x8 bn = *(const i32x8*)(Bbase + n * 2048);
      acc[0][n] = __builtin_amdgcn_mfma_scale_f32_16x16x128_f8f6f4(
          a0, bn, acc[0][n], 0, 0, 0, 0x7F7F7F7F, 0, 0x7F7F7F7F);
      acc[1][n] = __builtin_amdgcn_mfma_scale_f32_16x16x128_f8f6f4(
          a1, bn, acc[1][n], 0, 0, 0, 0x7F7F7F7F, 0, 0x7F7F7F7F);
      acc[2][n] = __builtin_amdgcn_mfma_scale_f32_16x16x128_f8f6f4(
          a2, bn, acc[2][n], 0, 0, 0, 0x7F7F7F7F, 0, 0x7F7F7F7F);
      acc[3][n] = __builtin_amdgcn_mfma_scale_f32_16x16x128_f8f6f4(
          a3, bn, acc[3][n], 0, 0, 0, 0x7F7F7F7F, 0, 0x7F7F7F7F);
    }
    __syncthreads();
  }

  // C/D layout: col = lane&15, row = (lane>>4)*4 + reg (shape-determined)
  // Row-max over this wave's 64 cols (group 2*jt+wn).
  #pragma unroll
  for (int m = 0; m < 4; ++m) {
    #pragma unroll
    for (int g = 0; g < 4; ++g) {
      float v = fmaxf(fmaxf(acc[m][0][g], acc[m][1][g]),
                      fmaxf(acc[m][2][g], acc[m][3][g]));
      v = fmaxf(v, __shfl_xor(v, 1));
      v = fmaxf(v, __shfl_xor(v, 2));
      v = fmaxf(v, __shfl_xor(v, 4));
      v = fmaxf(v, __shfl_xor(v, 8));
      if ((lane & 15) == 0) {
        int row = row0 + wm * 64 + m * 16 + (lane >> 4) * 4 + g;
        partialL[(size_t)row * NTILES + 2 * jt + wn] = v;
      }
    }
  }
  // Col-max over this wave's 64 rows (group 2*it+wm), written transposed.
  if (it != jt) {
    #pragma unroll
    for (int n = 0; n < 4; ++n) {
      float v = -1e30f;
      #pragma unroll
      for (int m = 0; m < 4; ++m)
        #pragma unroll
        for (int g = 0; g < 4; ++g) v = fmaxf(v, acc[m][n][g]);
      v = fmaxf(v, __shfl_xor(v, 16));
      v = fmaxf(v, __shfl_xor(v, 32));
      if (lane < 16) {
        int col = col0 + wn * 64 + n * 16 + lane;
        partialL[(size_t)col * NTILES + 2 * it + wm] = v;
      }
    }
  }
}

// ---------------------------------------------------------------------------
// Kernel 4: per row: for each of 12 combos, max over 9 q-groups per image c,
// d-transform (undo fp8 prescale), top-2 smallest over c != b; sum -> scores.
// ---------------------------------------------------------------------------
__global__ __launch_bounds__(256) void reduce_topk_kernel(
    const float* __restrict__ part,      // [NCOMBO][ROWS][NTILES]
    float* __restrict__ scores) {        // [ROWS]
  const int row = blockIdx.x * 256 + threadIdx.x;
  if (row >= ROWS) return;
  const int b = row / PP;
  float sum = 0.f;
  for (int k = 0; k < NCOMBO; ++k) {
    const float* pr = part + ((size_t)k * ROWS + row) * NTILES;
    float d1 = 1e30f, d2 = 1e30f;
    #pragma unroll
    for (int c = 0; c < BATCH; ++c) {
      if (c == b) continue;
      float md = pr[c * 9];
      #pragma unroll
      for (int q = 1; q < 9; ++q) md = fmaxf(md, pr[c * 9 + q]);
      float d = sqrtf(fmaxf(2.f - md * INV_PRESCALE2_X2, 0.f));
      if (d < d1) { d2 = d1; d1 = d; }
      else if (d < d2) { d2 = d; }
    }
    sum += 0.5f * (d1 + d2);
  }
  scores[row] = sum;
}

// ---------------------------------------------------------------------------
// Kernel 5 (fused): blocks 0..3527 = bilinear (align_corners) 24x24 -> 336x336
// scaled 1/12; blocks 3528..3535 = scores_image[b] = max_p scores[b,p] / 12.
// ---------------------------------------------------------------------------
__global__ __launch_bounds__(256) void final_kernel(
    const float* __restrict__ scores, float* __restrict__ out) {
  const int bid = blockIdx.x;
  const int t = threadIdx.x;
  if (bid < (BATCH * OH * OW) / 256) {
    const int idx = bid * 256 + t;
    const int b = idx / (OH * OW);
    const int rem = idx % (OH * OW);
    const int y = rem / OW, x = rem % OW;
    const float sc = (float)(23.0 / 335.0);
    const float ys = y * sc, xs = x * sc;
    const int y0 = (int)floorf(ys), x0 = (int)floorf(xs);
    const float wy = ys - (float)y0, wx = xs - (float)x0;
    const int y1 = min(y0 + 1, PHH - 1), x1 = min(x0 + 1, PWW - 1);
    const float* sb = scores + b * PP;
    const float f00 = sb[y0 * PWW + x0], f01 = sb[y0 * PWW + x1];
    const float f10 = sb[y1 * PWW + x0], f11 = sb[y1 * PWW + x1];
    const float v = f00 * (1.f - wy) * (1.f - wx) + f01 * (1.f - wy) * wx +
                    f10 * wy * (1.f - wx) + f11 * wy * wx;
    out[8 + idx] = v * (1.f / 12.f);
  } else {
    const int b = bid - (BATCH * OH * OW) / 256;
    float m = -1e30f;
    for (int p = t; p < PP; p += 256) m = fmaxf(m, scores[b * PP + p]);
    #pragma unroll
    for (int off = 32; off > 0; off >>= 1) m = fmaxf(m, __shfl_down(m, off));
    __shared__ float red[4];
    if ((t & 63) == 0) red[t >> 6] = m;
    __syncthreads();
    if (t == 0)
      out[b] = fmaxf(fmaxf(red[0], red[1]), fmaxf(red[2], red[3])) * (1.f / 12.f);
  }
}

// ---------------------------------------------------------------------------
extern "C" void kernel_launch(void* const* d_in, const int* in_sizes, int n_in,
                              void* d_out, int out_size, void* d_ws, size_t ws_size,
                              hipStream_t stream) {
  const float* feat = (const float*)d_in[0];     // [4][8][576][1024] f32
  float* out = (float*)d_out;                    // [8] ++ [8][336][336]
  char* ws = (char*)d_ws;

  // workspace layout (~148 MB of ~302 MB)
  const size_t NF_BYTES   = (size_t)NCOMBO * ROWS * DD;            // 56,623,104 (fp8)
  const size_t PART_BYTES = (size_t)NCOMBO * ROWS * NTILES * 4;    // 15,925,248
  const size_t SCR_BYTES  = (size_t)ROWS * 4;                      //     18,432
  const size_t H_BYTES    = (size_t)L_LAYERS * ROWS * DD * 2;      // 37,748,736
  unsigned char*  nf_all = (unsigned char*)ws;
  float*          part   = (float*)(ws + NF_BYTES);
  float*          scr    = (float*)(ws + NF_BYTES + PART_BYTES);
  unsigned short* h3     = (unsigned short*)(ws + NF_BYTES + PART_BYTES + SCR_BYTES);
  unsigned short* h5     = (unsigned short*)(ws + NF_BYTES + PART_BYTES + SCR_BYTES + H_BYTES);

  pool_kernel<<<dim3(16, BATCH, L_LAYERS * 2), 256, 0, stream>>>(feat, h3, h5);
  quant_kernel<<<dim3(ROWS, L_LAYERS), 256, 0, stream>>>(feat, h3, h5, nf_all);
  gemm_max_kernel<<<TOTBLK, 256, 0, stream>>>(nf_all, part);
  reduce_topk_kernel<<<(ROWS + 255) / 256, 256, 0, stream>>>(part, scr);
  final_kernel<<<(BATCH * OH * OW) / 256 + BATCH, 256, 0, stream>>>(scr, out);
}